// Round 12
// baseline (878.659 us; speedup 1.0000x reference)
//
#include <hip/hip_runtime.h>
#include <hip/hip_fp16.h>

// Problem constants (from reference)
#define SPP   16
#define SH    256
#define SW    256
#define HI    1024
#define WI    1024
#define CH    3
#define BATCH 4

#define TS    8     // 8x8 px tile, 1 px/lane, 16 spp in-lane
#define MAXD  46    // max bbox cols/rows at t=1 for an 8-px span
#define NPAD  2176  // 34 chunks of 64 px slots per LDS buffer (= MAXD*MAXD rounded up)
#define NTHR  64    // one wave per block; each wave owns 4 consecutive tiles

// tanh via v_exp_f32; |arg| <= ~1.2 here, abs error ~1e-6 (threshold 1.7e-2).
__device__ __forceinline__ float fast_tanh(float x) {
    const float e = __expf(2.0f * x);
    return (e - 1.0f) * __builtin_amdgcn_rcpf(e + 1.0f);
}

// R11 post-mortem: the invariant ~35us floor is HBM *duty cycle*, not
// efficiency — every variant phase-locks: waves stage (HBM burst) then
// sample (HBM idle, ~2/3 of lifetime) -> effective rate 6TB/s x 0.3 = the
// measured 1.8TB/s. This kernel pipelines ACROSS TILES within each wave:
// while sampling tile k from LDS buffer A, the staging chunks of tile k+1
// (reg-load -> cvt fp16 -> ds_write into buffer B) are interleaved between
// sample groups -> HBM load-issue is continuous over ~3/4 of the wave.
// 1024 blocks x 4 consecutive tiles (same tile row -> same image rows).
// Distinct __shared__ arrays A/B let LLVM prove no-alias, so sampling A is
// not serialized against the ds_writes to B.
__global__ __launch_bounds__(NTHR, 2) void foveated_pipe(
    const float* __restrict__ img,
    const float* __restrict__ t_ptr,
    const float* __restrict__ jitter,
    float* __restrict__ out)
{
    __shared__ __half2 RGa[NPAD];   // 8704 B
    __shared__ __half  Bpa[NPAD];   // 4352 B
    __shared__ __half2 RGb[NPAD];   // 8704 B
    __shared__ __half  Bpb[NPAD];   // 4352 B  -> 26112 B total, 6 blocks/CU cap

    // XCD slab swizzle: 1024 blocks -> 128 contiguous logical blocks per XCD.
    const int bid = blockIdx.x;
    const int L   = (bid & 7) * 128 + (bid >> 3);
    const int gt0 = L * 4;                 // first of 4 consecutive tiles
    const int b    = gt0 >> 10;            // 1024 tiles per batch (32x32)
    const int trow = (gt0 >> 5) & 31;      // all 4 tiles share trow & batch
    const int sy0  = trow * TS;
    const int sx00 = (gt0 & 31) * TS;      // tiles at sx00 + {0,8,16,24}

    const int lane = threadIdx.x;          // 0..63
    const int lx   = lane & 7;
    const int sy   = sy0 + (lane >> 3);

    const float step  = 2.0f / 256.0f;
    const float tt    = t_ptr[0];
    const float inv_s = __builtin_amdgcn_rcpf(fast_tanh(tt));

    auto gmap = [&](float p) {
        float g = (fast_tanh(tt * p) * inv_s + 1.0f) * 512.0f - 0.5f;
        return fminf(fmaxf(g, 0.0f), 1023.0f);
    };
    // Shared y-band (same trow for all 4 tiles)
    const float pym = -1.0f + sy0 * step;
    const int y_lo  = max((int)gmap(pym) - 1, 0);
    const int y_hi  = min((int)gmap(pym + TS * step) + 2, HI - 1);
    const int nrows = y_hi - y_lo + 1;

    // x edges of the 4 tiles (5 shared gmap evals)
    const float pxm = -1.0f + sx00 * step;
    const float e0 = gmap(pxm);
    const float e1 = gmap(pxm +  8 * step);
    const float e2 = gmap(pxm + 16 * step);
    const float e3 = gmap(pxm + 24 * step);
    const float e4 = gmap(pxm + 32 * step);
    const int xl0 = max((int)e0 - 1, 0), xh0 = min((int)e1 + 2, WI - 1);
    const int xl1 = max((int)e1 - 1, 0), xh1 = min((int)e2 + 2, WI - 1);
    const int xl2 = max((int)e2 - 1, 0), xh2 = min((int)e3 + 2, WI - 1);
    const int xl3 = max((int)e3 - 1, 0), xh3 = min((int)e4 + 2, WI - 1);
    const int nc0 = xh0 - xl0 + 1, nc1 = xh1 - xl1 + 1;
    const int nc2 = xh2 - xl2 + 1, nc3 = xh3 - xl3 + 1;
    const bool fits = (nrows > 0) && (nrows <= MAXD) &&
                      (nc0 > 0) && (nc0 <= MAXD) && (nc1 > 0) && (nc1 <= MAXD) &&
                      (nc2 > 0) && (nc2 <= MAXD) && (nc3 > 0) && (nc3 <= MAXD);

    const size_t plane = (size_t)HI * WI;
    const float* __restrict__ p0 = img + (size_t)(b * CH) * plane;
    const float* __restrict__ p1 = p0 + plane;
    const float* __restrict__ p2 = p1 + plane;

    const float py = -1.0f + sy * step;

    const float2* __restrict__ jit2 = (const float2*)jitter;
    const int jb0 = sy * SW + sx00 + lx;   // tile k: + 8*k

    float2 jA[16], jB[16];
    float acc0, acc1, acc2, dsum;

    // Mutable per-tile context for the sampling lambda (constant-folded per
    // call site after inlining; straight-line assignments).
    float cur_px = 0.0f;
    int   cur_xlo = 0, cur_nc = 1;
    const __half2* cur_RG = RGa;
    const __half*  cur_Bp = Bpa;

    auto sample_lds = [&](float jx, float jy) {
        const float posx = cur_px + jx * step;
        const float posy = py + jy * step;

        const float thx = fast_tanh(tt * posx);
        const float thy = fast_tanh(tt * posy);
        const float ddx = tt * (1.0f - thx * thx) * inv_s;
        const float ddy = tt * (1.0f - thy * thy) * inv_s;
        const float det = ddx * ddy;

        float gx = (thx * inv_s + 1.0f) * 512.0f - 0.5f;
        float gy = (thy * inv_s + 1.0f) * 512.0f - 0.5f;
        gx = fminf(fmaxf(gx, 0.0f), (float)(WI - 1));
        gy = fminf(fmaxf(gy, 0.0f), (float)(HI - 1));

        const int xb = min((int)gx, WI - 2);
        const int yb = min((int)gy, HI - 2);
        const float fx = gx - (float)xb;
        const float fy = gy - (float)yb;

        const float w00 = (1.0f - fx) * (1.0f - fy) * det;
        const float w01 = fx * (1.0f - fy) * det;
        const float w10 = (1.0f - fx) * fy * det;
        const float w11 = fx * fy * det;
        dsum += det;

        const int lidx = (yb - y_lo) * cur_nc + (xb - cur_xlo);
        const int l10  = lidx + cur_nc;

        const float2 f00 = __half22float2(cur_RG[lidx]);
        const float2 f01 = __half22float2(cur_RG[lidx + 1]);
        const float2 f10 = __half22float2(cur_RG[l10]);
        const float2 f11 = __half22float2(cur_RG[l10 + 1]);
        const float v00 = __half2float(cur_Bp[lidx]);
        const float v01 = __half2float(cur_Bp[lidx + 1]);
        const float v10 = __half2float(cur_Bp[l10]);
        const float v11 = __half2float(cur_Bp[l10 + 1]);

        acc0 += w00 * f00.x + w01 * f01.x + w10 * f10.x + w11 * f11.x;
        acc1 += w00 * f00.y + w01 * f01.y + w10 * f10.y + w11 * f11.y;
        acc2 += w00 * v00   + w01 * v01   + w10 * v10   + w11 * v11;
    };

    auto sample_glb = [&](float jx, float jy) {
        const float posx = cur_px + jx * step;
        const float posy = py + jy * step;

        const float thx = fast_tanh(tt * posx);
        const float thy = fast_tanh(tt * posy);
        const float ddx = tt * (1.0f - thx * thx) * inv_s;
        const float ddy = tt * (1.0f - thy * thy) * inv_s;
        const float det = ddx * ddy;

        float gx = (thx * inv_s + 1.0f) * 512.0f - 0.5f;
        float gy = (thy * inv_s + 1.0f) * 512.0f - 0.5f;
        gx = fminf(fmaxf(gx, 0.0f), (float)(WI - 1));
        gy = fminf(fmaxf(gy, 0.0f), (float)(HI - 1));

        const int xb = min((int)gx, WI - 2);
        const int yb = min((int)gy, HI - 2);
        const float fx = gx - (float)xb;
        const float fy = gy - (float)yb;

        const float w00 = (1.0f - fx) * (1.0f - fy) * det;
        const float w01 = fx * (1.0f - fy) * det;
        const float w10 = (1.0f - fx) * fy * det;
        const float w11 = fx * fy * det;
        dsum += det;

        const int i0 = yb * WI + xb;
        const int i1 = i0 + WI;
        { const float a0 = p0[i0], a1 = p0[i0 + 1], c0 = p0[i1], c1 = p0[i1 + 1];
          acc0 += a0 * w00 + a1 * w01 + c0 * w10 + c1 * w11; }
        { const float a0 = p1[i0], a1 = p1[i0 + 1], c0 = p1[i1], c1 = p1[i1 + 1];
          acc1 += a0 * w00 + a1 * w01 + c0 * w10 + c1 * w11; }
        { const float a0 = p2[i0], a1 = p2[i0 + 1], c0 = p2[i1], c1 = p2[i1 + 1];
          acc2 += a0 * w00 + a1 * w01 + c0 * w10 + c1 * w11; }
    };

    // ---- staging / sampling building blocks (all literal-indexed: rule #20) ----
    #define JLOAD(J, KOFF)                                                  \
        { _Pragma("unroll") for (int u = 0; u < 16; ++u)                    \
              J[u] = jit2[jb0 + (KOFF) + u * (SH * SW)]; }

    #define ISSUE(ARR, G, CNT, NIT, NC, MD, XLO, NPIX)                      \
        if ((G) * 7 < (NIT)) {                                              \
            _Pragma("unroll") for (int u = 0; u < (CNT); ++u) {             \
                const int i_ = min(((G) * 7 + u) * 64 + lane, (NPIX) - 1);  \
                const int r_ = (int)(((unsigned)i_ * (MD)) >> 22);          \
                const int c_ = i_ - r_ * (NC);                              \
                const int g_ = (y_lo + r_) * WI + ((XLO) + c_);             \
                ARR[u][0] = p0[g_]; ARR[u][1] = p1[g_]; ARR[u][2] = p2[g_]; \
            } }

    #define COMMIT(ARR, G, CNT, NIT, RGd, Bpd)                              \
        if ((G) * 7 < (NIT)) {                                              \
            _Pragma("unroll") for (int u = 0; u < (CNT); ++u) {             \
                const int s_ = ((G) * 7 + u) * 64 + lane;                   \
                RGd[s_] = __floats2half2_rn(ARR[u][0], ARR[u][1]);          \
                Bpd[s_] = __float2half_rn(ARR[u][2]);                       \
            } }

    #define WAITLDS                                                         \
        asm volatile("s_waitcnt lgkmcnt(0)" ::: "memory");                  \
        __builtin_amdgcn_sched_barrier(0)

    #define SETTILE(K, XLO, NC, RGc, Bpc)                                   \
        cur_px = -1.0f + (sx00 + (K) * 8 + lx) * step;                      \
        cur_xlo = (XLO); cur_nc = (NC); cur_RG = (RGc); cur_Bp = (Bpc);     \
        acc0 = acc1 = acc2 = dsum = 0.0f

    #define S4(J, A_, B_, C_, D_)                                           \
        sample_lds(J[A_].x, J[A_].y); sample_lds(J[B_].x, J[B_].y);         \
        sample_lds(J[C_].x, J[C_].y); sample_lds(J[D_].x, J[D_].y)

    #define STORE(K)                                                        \
        { const float inv_d = 1.0f / dsum;                                  \
          const int pix = sy * SW + sx00 + (K) * 8 + lx;                    \
          const size_t ob = (size_t)b * CH * (SH * SW) + pix;               \
          out[ob]              = acc0 * inv_d;                              \
          out[ob + SH * SW]    = acc1 * inv_d;                              \
          out[ob + 2 * SH * SW] = acc2 * inv_d; }

    if (fits) {
        const int np0_ = nrows * nc0, ni0_ = (np0_ + 63) >> 6;
        const int np1_ = nrows * nc1, ni1_ = (np1_ + 63) >> 6;
        const int np2_ = nrows * nc2, ni2_ = (np2_ + 63) >> 6;
        const int np3_ = nrows * nc3, ni3_ = (np3_ + 63) >> 6;
        const unsigned md0_ = (1u << 22) / (unsigned)nc0 + 1u;
        const unsigned md1_ = (1u << 22) / (unsigned)nc1 + 1u;
        const unsigned md2_ = (1u << 22) / (unsigned)nc2 + 1u;
        const unsigned md3_ = (1u << 22) / (unsigned)nc3 + 1u;

        float LA[7][3], LB[7][3];

        JLOAD(jA, 0);
        // ---- prologue: stage tile0 -> A (2-deep reg pipeline) ----
        ISSUE (LA, 0, 7, ni0_, nc0, md0_, xl0, np0_);
        ISSUE (LB, 1, 7, ni0_, nc0, md0_, xl0, np0_);
        COMMIT(LA, 0, 7, ni0_, RGa, Bpa);
        ISSUE (LA, 2, 7, ni0_, nc0, md0_, xl0, np0_);
        COMMIT(LB, 1, 7, ni0_, RGa, Bpa);
        ISSUE (LB, 3, 7, ni0_, nc0, md0_, xl0, np0_);
        COMMIT(LA, 2, 7, ni0_, RGa, Bpa);
        ISSUE (LA, 4, 6, ni0_, nc0, md0_, xl0, np0_);
        COMMIT(LB, 3, 7, ni0_, RGa, Bpa);
        COMMIT(LA, 4, 6, ni0_, RGa, Bpa);
        WAITLDS;

        // ---- tile 0: sample A/jA, stage tile1 -> B ----
        SETTILE(0, xl0, nc0, RGa, Bpa);
        ISSUE (LA, 0, 7, ni1_, nc1, md1_, xl1, np1_);
        S4(jA, 0, 1, 2, 3);
        COMMIT(LA, 0, 7, ni1_, RGb, Bpb);
        ISSUE (LB, 1, 7, ni1_, nc1, md1_, xl1, np1_);
        S4(jA, 4, 5, 6, 7);
        COMMIT(LB, 1, 7, ni1_, RGb, Bpb);
        ISSUE (LA, 2, 7, ni1_, nc1, md1_, xl1, np1_);
        JLOAD(jB, 8);
        S4(jA, 8, 9, 10, 11);
        COMMIT(LA, 2, 7, ni1_, RGb, Bpb);
        ISSUE (LB, 3, 7, ni1_, nc1, md1_, xl1, np1_);
        S4(jA, 12, 13, 14, 15);
        COMMIT(LB, 3, 7, ni1_, RGb, Bpb);
        ISSUE (LA, 4, 6, ni1_, nc1, md1_, xl1, np1_);
        STORE(0);
        COMMIT(LA, 4, 6, ni1_, RGb, Bpb);
        WAITLDS;

        // ---- tile 1: sample B/jB, stage tile2 -> A ----
        SETTILE(1, xl1, nc1, RGb, Bpb);
        ISSUE (LA, 0, 7, ni2_, nc2, md2_, xl2, np2_);
        S4(jB, 0, 1, 2, 3);
        COMMIT(LA, 0, 7, ni2_, RGa, Bpa);
        ISSUE (LB, 1, 7, ni2_, nc2, md2_, xl2, np2_);
        S4(jB, 4, 5, 6, 7);
        COMMIT(LB, 1, 7, ni2_, RGa, Bpa);
        ISSUE (LA, 2, 7, ni2_, nc2, md2_, xl2, np2_);
        JLOAD(jA, 16);
        S4(jB, 8, 9, 10, 11);
        COMMIT(LA, 2, 7, ni2_, RGa, Bpa);
        ISSUE (LB, 3, 7, ni2_, nc2, md2_, xl2, np2_);
        S4(jB, 12, 13, 14, 15);
        COMMIT(LB, 3, 7, ni2_, RGa, Bpa);
        ISSUE (LA, 4, 6, ni2_, nc2, md2_, xl2, np2_);
        STORE(1);
        COMMIT(LA, 4, 6, ni2_, RGa, Bpa);
        WAITLDS;

        // ---- tile 2: sample A/jA, stage tile3 -> B ----
        SETTILE(2, xl2, nc2, RGa, Bpa);
        ISSUE (LA, 0, 7, ni3_, nc3, md3_, xl3, np3_);
        S4(jA, 0, 1, 2, 3);
        COMMIT(LA, 0, 7, ni3_, RGb, Bpb);
        ISSUE (LB, 1, 7, ni3_, nc3, md3_, xl3, np3_);
        S4(jA, 4, 5, 6, 7);
        COMMIT(LB, 1, 7, ni3_, RGb, Bpb);
        ISSUE (LA, 2, 7, ni3_, nc3, md3_, xl3, np3_);
        JLOAD(jB, 24);
        S4(jA, 8, 9, 10, 11);
        COMMIT(LA, 2, 7, ni3_, RGb, Bpb);
        ISSUE (LB, 3, 7, ni3_, nc3, md3_, xl3, np3_);
        S4(jA, 12, 13, 14, 15);
        COMMIT(LB, 3, 7, ni3_, RGb, Bpb);
        ISSUE (LA, 4, 6, ni3_, nc3, md3_, xl3, np3_);
        STORE(2);
        COMMIT(LA, 4, 6, ni3_, RGb, Bpb);
        WAITLDS;

        // ---- tile 3: sample B/jB (no staging left) ----
        SETTILE(3, xl3, nc3, RGb, Bpb);
        S4(jB, 0, 1, 2, 3);
        S4(jB, 4, 5, 6, 7);
        S4(jB, 8, 9, 10, 11);
        S4(jB, 12, 13, 14, 15);
        STORE(3);
    } else {
        // ---- Fallback: direct global gathers (never taken at t=1) ----
        for (int k = 0; k < 4; ++k) {
            JLOAD(jA, 8 * k);
            cur_px = -1.0f + (sx00 + k * 8 + lx) * step;
            acc0 = acc1 = acc2 = dsum = 0.0f;
            #pragma unroll
            for (int u = 0; u < 16; ++u) sample_glb(jA[u].x, jA[u].y);
            const float inv_d = 1.0f / dsum;
            const int pix = sy * SW + sx00 + k * 8 + lx;
            const size_t ob = (size_t)b * CH * (SH * SW) + pix;
            out[ob]               = acc0 * inv_d;
            out[ob + SH * SW]     = acc1 * inv_d;
            out[ob + 2 * SH * SW] = acc2 * inv_d;
        }
    }

    #undef JLOAD
    #undef ISSUE
    #undef COMMIT
    #undef WAITLDS
    #undef SETTILE
    #undef S4
    #undef STORE
}

extern "C" void kernel_launch(void* const* d_in, const int* in_sizes, int n_in,
                              void* d_out, int out_size, void* d_ws, size_t ws_size,
                              hipStream_t stream) {
    const float* img    = (const float*)d_in[0];
    const float* t      = (const float*)d_in[1];
    const float* jitter = (const float*)d_in[2];
    float* out          = (float*)d_out;

    // 4096 tiles of 8x8 px, 4 per wave -> 1024 blocks x 64 threads
    hipLaunchKernelGGL(foveated_pipe, dim3(1024), dim3(NTHR), 0, stream,
                       img, t, jitter, out);
}

// Round 15
// 125.051 us; speedup vs baseline: 7.0264x; 7.0264x over previous
//
#include <hip/hip_runtime.h>
#include <hip/hip_fp16.h>

// Problem constants (from reference)
#define SPP   16
#define SH    256
#define SW    256
#define HI    1024
#define WI    1024
#define CH    3
#define BATCH 4

#define TS    8     // 8x8 px tile, 1 px/lane, 16 spp in-lane
#define MAXD  46    // max bbox cols/rows at t=1 for an 8-px span
#define NPAD  2176  // 34 chunks of 64 dwords per LDS plane
#define NTHR  64    // one wave per block; each wave pipelines 4 tiles
#define SS    (SH * SW)

#define AS1C(p) ((const __attribute__((address_space(1))) void*)(p))
#define AS3(p)  ((__attribute__((address_space(3))) void*)(p))

// tanh via v_exp_f32; |arg| <= ~1.2 here, abs error ~1e-6 (threshold 1.7e-2).
__device__ __forceinline__ float fast_tanh(float x) {
    const float e = __expf(2.0f * x);
    return (e - 1.0f) * __builtin_amdgcn_rcpf(e + 1.0f);
}

// R12 post-mortem: reg-staged tile pipeline spilled (WRITE 1.6GB scratch,
// VGPR capped 128) -> duty-cycle theory untested. This version pipelines with
// ZERO-register staging: async global_load_lds DMA (R8's proven path) into an
// f32 double buffer. Wave owns 4 consecutive tiles; while sampling tile k
// from buffer A, tile k+1's 102 DMA loads + 16 jitter loads fly into B; one
// vmcnt(0) per boundary. HBM issue is continuous over ~3/4 of wave lifetime
// (vs ~1/3 phase-locked in R8). Per-tile sample state passed as ARGUMENTS
// (R12's mutable captures were the scratch magnet). launch_bounds(64,2):
// VGPR cap 256 (no spill); occupancy LDS-bound at 3 blocks/CU either way.
// R14: fixed SAMPLE16 token-pasting (J##0.x lexed "0.x" as one pp-number ->
// invalid paste). Now "J##0 .x". No semantic change vs R13.
__global__ __launch_bounds__(NTHR, 2) void foveated_dpipe(
    const float* __restrict__ img,
    const float* __restrict__ t_ptr,
    const float* __restrict__ jitter,
    float* __restrict__ out)
{
    __shared__ float A0[NPAD], A1[NPAD], A2[NPAD];   // buffer A: 26112 B
    __shared__ float B0[NPAD], B1[NPAD], B2[NPAD];   // buffer B: 26112 B

    // XCD slab swizzle: 1024 blocks -> 128 contiguous logical blocks per XCD.
    const int bid  = blockIdx.x;
    const int L    = (bid & 7) * 128 + (bid >> 3);
    const int gt0  = L * 4;                 // 4 consecutive tiles, same row
    const int b    = gt0 >> 10;             // 1024 tiles per batch (32x32)
    const int trow = (gt0 >> 5) & 31;
    const int sy0  = trow * TS;
    const int sx00 = (gt0 & 31) * TS;       // tiles at sx00 + {0,8,16,24}

    const int lane = threadIdx.x;           // 0..63
    const int lx   = lane & 7;
    const int sy   = sy0 + (lane >> 3);

    const float step  = 2.0f / 256.0f;
    const float tt    = t_ptr[0];
    const float inv_s = __builtin_amdgcn_rcpf(fast_tanh(tt));

    auto gmap = [&](float p) {
        float g = (fast_tanh(tt * p) * inv_s + 1.0f) * 512.0f - 0.5f;
        return fminf(fmaxf(g, 0.0f), 1023.0f);
    };

    // Shared y-band (all 4 tiles share the sensor-row band)
    const float pym = -1.0f + sy0 * step;
    const int y_lo  = max((int)gmap(pym) - 1, 0);
    const int y_hi  = min((int)gmap(pym + TS * step) + 2, HI - 1);
    const int nrows = y_hi - y_lo + 1;

    // x edges of the 4 tiles (5 gmap evals)
    const float pxm = -1.0f + sx00 * step;
    const float e0 = gmap(pxm);
    const float e1 = gmap(pxm +  8 * step);
    const float e2 = gmap(pxm + 16 * step);
    const float e3 = gmap(pxm + 24 * step);
    const float e4 = gmap(pxm + 32 * step);
    const int xl0 = max((int)e0 - 1, 0), xh0 = min((int)e1 + 2, WI - 1);
    const int xl1 = max((int)e1 - 1, 0), xh1 = min((int)e2 + 2, WI - 1);
    const int xl2 = max((int)e2 - 1, 0), xh2 = min((int)e3 + 2, WI - 1);
    const int xl3 = max((int)e3 - 1, 0), xh3 = min((int)e4 + 2, WI - 1);
    const int nc0 = xh0 - xl0 + 1, nc1 = xh1 - xl1 + 1;
    const int nc2 = xh2 - xl2 + 1, nc3 = xh3 - xl3 + 1;
    const bool fits = (nrows > 0) && (nrows <= MAXD) &&
                      (nc0 > 0) && (nc0 <= MAXD) && (nc1 > 0) && (nc1 <= MAXD) &&
                      (nc2 > 0) && (nc2 <= MAXD) && (nc3 > 0) && (nc3 <= MAXD);

    const int np0 = nrows * nc0, ni0 = (np0 + 63) >> 6;
    const int np1 = nrows * nc1, ni1 = (np1 + 63) >> 6;
    const int np2 = nrows * nc2, ni2 = (np2 + 63) >> 6;
    const int np3 = nrows * nc3, ni3 = (np3 + 63) >> 6;
    const unsigned md0 = (1u << 22) / (unsigned)nc0 + 1u;
    const unsigned md1 = (1u << 22) / (unsigned)nc1 + 1u;
    const unsigned md2 = (1u << 22) / (unsigned)nc2 + 1u;
    const unsigned md3 = (1u << 22) / (unsigned)nc3 + 1u;

    const size_t plane = (size_t)HI * WI;
    const float* __restrict__ p0 = img + (size_t)(b * CH) * plane;
    const float* __restrict__ p1 = p0 + plane;
    const float* __restrict__ p2 = p1 + plane;

    const float py = -1.0f + sy * step;

    const float2* __restrict__ jit2 = (const float2*)jitter;
    const int jb0 = sy * SW + sx00 + lx;    // tile k: spatial offset +8k

    // Named jitter registers, double-buffered across tiles (rule #20).
    float2 jA0, jA1, jA2, jA3, jA4, jA5, jA6, jA7,
           jA8, jA9, jA10, jA11, jA12, jA13, jA14, jA15;
    float2 jB0, jB1, jB2, jB3, jB4, jB5, jB6, jB7,
           jB8, jB9, jB10, jB11, jB12, jB13, jB14, jB15;

    float acc0, acc1, acc2, dsum;

    // Per-tile state passed as ARGUMENTS (no mutable captures -> no scratch).
    auto sample = [&](float jx, float jy, float pxb, int xlo, int nc,
                      const float* Q0, const float* Q1, const float* Q2) {
        const float posx = pxb + jx * step;
        const float posy = py + jy * step;

        const float thx = fast_tanh(tt * posx);
        const float thy = fast_tanh(tt * posy);
        const float ddx = tt * (1.0f - thx * thx) * inv_s;
        const float ddy = tt * (1.0f - thy * thy) * inv_s;
        const float det = ddx * ddy;

        float gx = (thx * inv_s + 1.0f) * 512.0f - 0.5f;
        float gy = (thy * inv_s + 1.0f) * 512.0f - 0.5f;
        gx = fminf(fmaxf(gx, 0.0f), (float)(WI - 1));
        gy = fminf(fmaxf(gy, 0.0f), (float)(HI - 1));

        const int xb = min((int)gx, WI - 2);
        const int yb = min((int)gy, HI - 2);
        const float fx = gx - (float)xb;
        const float fy = gy - (float)yb;

        const float w00 = (1.0f - fx) * (1.0f - fy) * det;
        const float w01 = fx * (1.0f - fy) * det;
        const float w10 = (1.0f - fx) * fy * det;
        const float w11 = fx * fy * det;
        dsum += det;

        const int lidx = (yb - y_lo) * nc + (xb - xlo);
        const int l10  = lidx + nc;
        acc0 += w00 * Q0[lidx] + w01 * Q0[lidx + 1] + w10 * Q0[l10] + w11 * Q0[l10 + 1];
        acc1 += w00 * Q1[lidx] + w01 * Q1[lidx + 1] + w10 * Q1[l10] + w11 * Q1[l10 + 1];
        acc2 += w00 * Q2[lidx] + w01 * Q2[lidx + 1] + w10 * Q2[l10] + w11 * Q2[l10 + 1];
    };

    auto sample_glb = [&](float jx, float jy, float pxb) {
        const float posx = pxb + jx * step;
        const float posy = py + jy * step;

        const float thx = fast_tanh(tt * posx);
        const float thy = fast_tanh(tt * posy);
        const float ddx = tt * (1.0f - thx * thx) * inv_s;
        const float ddy = tt * (1.0f - thy * thy) * inv_s;
        const float det = ddx * ddy;

        float gx = (thx * inv_s + 1.0f) * 512.0f - 0.5f;
        float gy = (thy * inv_s + 1.0f) * 512.0f - 0.5f;
        gx = fminf(fmaxf(gx, 0.0f), (float)(WI - 1));
        gy = fminf(fmaxf(gy, 0.0f), (float)(HI - 1));

        const int xb = min((int)gx, WI - 2);
        const int yb = min((int)gy, HI - 2);
        const float fx = gx - (float)xb;
        const float fy = gy - (float)yb;

        const float w00 = (1.0f - fx) * (1.0f - fy) * det;
        const float w01 = fx * (1.0f - fy) * det;
        const float w10 = (1.0f - fx) * fy * det;
        const float w11 = fx * fy * det;
        dsum += det;

        const int i0 = yb * WI + xb;
        const int i1 = i0 + WI;
        { const float a0 = p0[i0], a1 = p0[i0 + 1], c0 = p0[i1], c1 = p0[i1 + 1];
          acc0 += a0 * w00 + a1 * w01 + c0 * w10 + c1 * w11; }
        { const float a0 = p1[i0], a1 = p1[i0 + 1], c0 = p1[i1], c1 = p1[i1 + 1];
          acc1 += a0 * w00 + a1 * w01 + c0 * w10 + c1 * w11; }
        { const float a0 = p2[i0], a1 = p2[i0 + 1], c0 = p2[i1], c1 = p2[i1 + 1];
          acc2 += a0 * w00 + a1 * w01 + c0 * w10 + c1 * w11; }
    };

    #define JLOAD(P, KOFF)                                                   \
        P##0  = jit2[jb0 + (KOFF)];            P##1  = jit2[jb0 + (KOFF) + 1 * SS];  \
        P##2  = jit2[jb0 + (KOFF) + 2 * SS];   P##3  = jit2[jb0 + (KOFF) + 3 * SS];  \
        P##4  = jit2[jb0 + (KOFF) + 4 * SS];   P##5  = jit2[jb0 + (KOFF) + 5 * SS];  \
        P##6  = jit2[jb0 + (KOFF) + 6 * SS];   P##7  = jit2[jb0 + (KOFF) + 7 * SS];  \
        P##8  = jit2[jb0 + (KOFF) + 8 * SS];   P##9  = jit2[jb0 + (KOFF) + 9 * SS];  \
        P##10 = jit2[jb0 + (KOFF) + 10 * SS];  P##11 = jit2[jb0 + (KOFF) + 11 * SS]; \
        P##12 = jit2[jb0 + (KOFF) + 12 * SS];  P##13 = jit2[jb0 + (KOFF) + 13 * SS]; \
        P##14 = jit2[jb0 + (KOFF) + 14 * SS];  P##15 = jit2[jb0 + (KOFF) + 15 * SS];

    // Async DMA stage: fire-and-forget, zero data registers (R8's proven path).
    // Source index clamped (dup reads hit cache); LDS slot UNclamped (unique).
    #define STAGE(D0, D1, D2, XLO, NC, NP, NI, MD)                           \
        _Pragma("unroll")                                                    \
        for (int kk = 0; kk < 34; ++kk) {                                    \
            if (kk < (NI)) {                                                 \
                const int i_ = min(kk * 64 + lane, (NP) - 1);                \
                const int r_ = (int)(((unsigned)i_ * (MD)) >> 22);           \
                const int c_ = i_ - r_ * (NC);                               \
                const int g_ = (y_lo + r_) * WI + ((XLO) + c_);              \
                __builtin_amdgcn_global_load_lds(AS1C(p0 + g_), AS3(D0 + kk * 64), 4, 0, 0); \
                __builtin_amdgcn_global_load_lds(AS1C(p1 + g_), AS3(D1 + kk * 64), 4, 0, 0); \
                __builtin_amdgcn_global_load_lds(AS1C(p2 + g_), AS3(D2 + kk * 64), 4, 0, 0); \
            } }

    #define VMCNT0                                                           \
        asm volatile("s_waitcnt vmcnt(0)" ::: "memory");                     \
        __builtin_amdgcn_sched_barrier(0)

    // NOTE: "J##0 .x" (space before .x) — "0.x" would lex as one pp-number.
    #define SAMPLE16(J, PXB_, XLO_, NC_, Q0_, Q1_, Q2_)                      \
        acc0 = acc1 = acc2 = dsum = 0.0f;                                    \
        sample(J##0 .x,  J##0 .y,  PXB_, XLO_, NC_, Q0_, Q1_, Q2_);          \
        sample(J##1 .x,  J##1 .y,  PXB_, XLO_, NC_, Q0_, Q1_, Q2_);          \
        sample(J##2 .x,  J##2 .y,  PXB_, XLO_, NC_, Q0_, Q1_, Q2_);          \
        sample(J##3 .x,  J##3 .y,  PXB_, XLO_, NC_, Q0_, Q1_, Q2_);          \
        sample(J##4 .x,  J##4 .y,  PXB_, XLO_, NC_, Q0_, Q1_, Q2_);          \
        sample(J##5 .x,  J##5 .y,  PXB_, XLO_, NC_, Q0_, Q1_, Q2_);          \
        sample(J##6 .x,  J##6 .y,  PXB_, XLO_, NC_, Q0_, Q1_, Q2_);          \
        sample(J##7 .x,  J##7 .y,  PXB_, XLO_, NC_, Q0_, Q1_, Q2_);          \
        sample(J##8 .x,  J##8 .y,  PXB_, XLO_, NC_, Q0_, Q1_, Q2_);          \
        sample(J##9 .x,  J##9 .y,  PXB_, XLO_, NC_, Q0_, Q1_, Q2_);          \
        sample(J##10 .x, J##10 .y, PXB_, XLO_, NC_, Q0_, Q1_, Q2_);          \
        sample(J##11 .x, J##11 .y, PXB_, XLO_, NC_, Q0_, Q1_, Q2_);          \
        sample(J##12 .x, J##12 .y, PXB_, XLO_, NC_, Q0_, Q1_, Q2_);          \
        sample(J##13 .x, J##13 .y, PXB_, XLO_, NC_, Q0_, Q1_, Q2_);          \
        sample(J##14 .x, J##14 .y, PXB_, XLO_, NC_, Q0_, Q1_, Q2_);          \
        sample(J##15 .x, J##15 .y, PXB_, XLO_, NC_, Q0_, Q1_, Q2_);

    #define STORE(K)                                                         \
        { const float inv_d = 1.0f / dsum;                                   \
          const int pix = sy * SW + sx00 + (K) * 8 + lx;                     \
          const size_t ob = (size_t)b * CH * SS + pix;                       \
          out[ob]          = acc0 * inv_d;                                   \
          out[ob + SS]     = acc1 * inv_d;                                   \
          out[ob + 2 * SS] = acc2 * inv_d; }

    #define PXB(K) (-1.0f + (sx00 + (K) * 8 + lx) * step)

    if (fits) {
        // ---- prologue: tile0 -> A (only exposed HBM wait of the wave) ----
        JLOAD(jA, 0);
        STAGE(A0, A1, A2, xl0, nc0, np0, ni0, md0);
        VMCNT0;

        // ---- tile0: sample A; tile1 DMA -> B flies underneath ----
        JLOAD(jB, 8);
        STAGE(B0, B1, B2, xl1, nc1, np1, ni1, md1);
        SAMPLE16(jA, PXB(0), xl0, nc0, A0, A1, A2);
        STORE(0);
        VMCNT0;

        // ---- tile1: sample B; tile2 DMA -> A flies underneath ----
        JLOAD(jA, 16);
        STAGE(A0, A1, A2, xl2, nc2, np2, ni2, md2);
        SAMPLE16(jB, PXB(1), xl1, nc1, B0, B1, B2);
        STORE(1);
        VMCNT0;

        // ---- tile2: sample A; tile3 DMA -> B flies underneath ----
        JLOAD(jB, 24);
        STAGE(B0, B1, B2, xl3, nc3, np3, ni3, md3);
        SAMPLE16(jA, PXB(2), xl2, nc2, A0, A1, A2);
        STORE(2);
        VMCNT0;

        // ---- tile3: sample B (nothing left to stage) ----
        SAMPLE16(jB, PXB(3), xl3, nc3, B0, B1, B2);
        STORE(3);
    } else {
        // ---- Fallback: direct global gathers (never taken at t=1) ----
        for (int k = 0; k < 4; ++k) {
            JLOAD(jA, 8 * k);
            acc0 = acc1 = acc2 = dsum = 0.0f;
            const float pxb = -1.0f + (sx00 + k * 8 + lx) * step;
            sample_glb(jA0.x,  jA0.y,  pxb);  sample_glb(jA1.x,  jA1.y,  pxb);
            sample_glb(jA2.x,  jA2.y,  pxb);  sample_glb(jA3.x,  jA3.y,  pxb);
            sample_glb(jA4.x,  jA4.y,  pxb);  sample_glb(jA5.x,  jA5.y,  pxb);
            sample_glb(jA6.x,  jA6.y,  pxb);  sample_glb(jA7.x,  jA7.y,  pxb);
            sample_glb(jA8.x,  jA8.y,  pxb);  sample_glb(jA9.x,  jA9.y,  pxb);
            sample_glb(jA10.x, jA10.y, pxb);  sample_glb(jA11.x, jA11.y, pxb);
            sample_glb(jA12.x, jA12.y, pxb);  sample_glb(jA13.x, jA13.y, pxb);
            sample_glb(jA14.x, jA14.y, pxb);  sample_glb(jA15.x, jA15.y, pxb);
            const float inv_d = 1.0f / dsum;
            const int pix = sy * SW + sx00 + k * 8 + lx;
            const size_t ob = (size_t)b * CH * SS + pix;
            out[ob]          = acc0 * inv_d;
            out[ob + SS]     = acc1 * inv_d;
            out[ob + 2 * SS] = acc2 * inv_d;
        }
    }

    #undef JLOAD
    #undef STAGE
    #undef VMCNT0
    #undef SAMPLE16
    #undef STORE
    #undef PXB
}

extern "C" void kernel_launch(void* const* d_in, const int* in_sizes, int n_in,
                              void* d_out, int out_size, void* d_ws, size_t ws_size,
                              hipStream_t stream) {
    const float* img    = (const float*)d_in[0];
    const float* t      = (const float*)d_in[1];
    const float* jitter = (const float*)d_in[2];
    float* out          = (float*)d_out;

    // 4096 tiles of 8x8 px, 4 per wave -> 1024 blocks x 64 threads
    hipLaunchKernelGGL(foveated_dpipe, dim3(1024), dim3(NTHR), 0, stream,
                       img, t, jitter, out);
}

// Round 16
// 108.463 us; speedup vs baseline: 8.1010x; 1.1529x over previous
//
#include <hip/hip_runtime.h>
#include <hip/hip_fp16.h>

// Problem constants (from reference)
#define SPP   16
#define SH    256
#define SW    256
#define HI    1024
#define WI    1024
#define CH    3
#define BATCH 4

#define MAXC  46    // max bbox cols at t=1 for an 8-px horizontal span
#define MAXR  26    // max bbox rows at t=1 for a 4-px vertical span
#define NPAD  1216  // 19 chunks of 64 dwords per LDS plane (>= 46*26=1196)
#define NITER 19
#define NTHR  64    // one wave per block; wave chains 8 tiles of 8x4 px
#define SS    (SH * SW)

#define AS1C(p) ((const __attribute__((address_space(1))) void*)(p))
#define AS3(p)  ((__attribute__((address_space(3))) void*)(p))

// tanh via v_exp_f32; |arg| <= ~1.2 here, abs error ~1e-6 (threshold 1.7e-2).
__device__ __forceinline__ float fast_tanh(float x) {
    const float e = __expf(2.0f * x);
    return (e - 1.0f) * __builtin_amdgcn_rcpf(e + 1.0f);
}

// R15 post-mortem: duty-cycle pipeline was right but tested at 2 waves/CU
// (grid 4/CU vs LDS cap 3 -> 3+1 rounds). This version sizes for FULL
// residency: 8x4 tiles (f32 dbuf = 28.5 KB -> cap 5/CU), 8 tiles per wave,
// 1024 blocks = 4 waves/CU <= cap -> whole grid co-resident, zero rounds.
// Every wave alternates {57-load DMA burst} / {sample phase} continuously ->
// device-wide HBM issue is spread over the whole kernel instead of a global
// stage-then-sample phase-lock (the measured ~34us floor = serial pipe sum).
// 2 lanes/px (spp 8/8 split via lane>>5), shfl_xor(32) combine.
__global__ __launch_bounds__(NTHR, 2) void foveated_chain8(
    const float* __restrict__ img,
    const float* __restrict__ t_ptr,
    const float* __restrict__ jitter,
    float* __restrict__ out)
{
    __shared__ float A0[NPAD], A1[NPAD], A2[NPAD];   // buffer A: 14592 B
    __shared__ float B0[NPAD], B1[NPAD], B2[NPAD];   // buffer B: 14592 B

    // XCD slab swizzle: 1024 blocks -> 128 contiguous logical blocks per XCD.
    const int bid  = blockIdx.x;
    const int L    = (bid & 7) * 128 + (bid >> 3);
    const int gt0  = L * 8;                 // 8 consecutive tiles, same row
    const int b    = gt0 >> 11;             // 2048 tiles per batch (32x64)
    const int rem  = gt0 & 2047;
    const int trow = rem >> 5;              // 0..63 (4-px tile rows)
    const int tc0  = rem & 31;              // {0,8,16,24}
    const int sy0  = trow * 4;
    const int sx00 = tc0 * 8;               // tiles at sx00 + 8*{0..7}

    const int lane = threadIdx.x;           // 0..63
    const int h    = lane >> 5;             // spp half: 0 -> 0..7, 1 -> 8..15
    const int p    = lane & 31;             // pixel in 8x4 tile
    const int lx   = p & 7;
    const int sy   = sy0 + (p >> 3);

    const float step  = 2.0f / 256.0f;
    const float tt    = t_ptr[0];
    const float inv_s = __builtin_amdgcn_rcpf(fast_tanh(tt));

    auto gmap = [&](float pp) {
        float g = (fast_tanh(tt * pp) * inv_s + 1.0f) * 512.0f - 0.5f;
        return fminf(fmaxf(g, 0.0f), 1023.0f);
    };

    // Shared y-band (all 8 tiles share the 4-sensor-row band)
    const float pym = -1.0f + sy0 * step;
    const int y_lo  = max((int)gmap(pym) - 1, 0);
    const int y_hi  = min((int)gmap(pym + 4 * step) + 2, HI - 1);
    const int nrows = y_hi - y_lo + 1;

    // x edges of the 8 tiles: 9 named evals (straight-line, rule #20)
    const float pxm = -1.0f + sx00 * step;
    const float E0 = gmap(pxm);
    const float E1 = gmap(pxm +  8 * step);
    const float E2 = gmap(pxm + 16 * step);
    const float E3 = gmap(pxm + 24 * step);
    const float E4 = gmap(pxm + 32 * step);
    const float E5 = gmap(pxm + 40 * step);
    const float E6 = gmap(pxm + 48 * step);
    const float E7 = gmap(pxm + 56 * step);
    const float E8 = gmap(pxm + 64 * step);

    #define TPAR(K, KN)                                                      \
        const int xl##K = max((int)E##K - 1, 0);                             \
        const int nc##K = min((int)E##KN + 2, WI - 1) - xl##K + 1;
    TPAR(0, 1) TPAR(1, 2) TPAR(2, 3) TPAR(3, 4)
    TPAR(4, 5) TPAR(5, 6) TPAR(6, 7) TPAR(7, 8)
    #undef TPAR

    bool fits = (nrows > 0) && (nrows <= MAXR);
    fits = fits && (nc0 > 0) && (nc0 <= MAXC) && (nc1 > 0) && (nc1 <= MAXC);
    fits = fits && (nc2 > 0) && (nc2 <= MAXC) && (nc3 > 0) && (nc3 <= MAXC);
    fits = fits && (nc4 > 0) && (nc4 <= MAXC) && (nc5 > 0) && (nc5 <= MAXC);
    fits = fits && (nc6 > 0) && (nc6 <= MAXC) && (nc7 > 0) && (nc7 <= MAXC);

    const size_t plane = (size_t)HI * WI;
    const float* __restrict__ p0 = img + (size_t)(b * CH) * plane;
    const float* __restrict__ p1 = p0 + plane;
    const float* __restrict__ p2 = p1 + plane;

    const float py = -1.0f + sy * step;

    const float2* __restrict__ jit2 = (const float2*)jitter;
    const int jb0 = h * 8 * SS + sy * SW + sx00 + lx;   // tile K: +8K spatial

    // Named jitter registers, double-buffered across tiles (rule #20).
    float2 jA0, jA1, jA2, jA3, jA4, jA5, jA6, jA7;
    float2 jB0, jB1, jB2, jB3, jB4, jB5, jB6, jB7;

    float acc0, acc1, acc2, dsum;

    // Per-tile state passed as ARGUMENTS (no mutable captures -> no scratch).
    auto sample = [&](float jx, float jy, float pxb, int xlo, int nc,
                      const float* Q0, const float* Q1, const float* Q2) {
        const float posx = pxb + jx * step;
        const float posy = py + jy * step;

        const float thx = fast_tanh(tt * posx);
        const float thy = fast_tanh(tt * posy);
        const float ddx = tt * (1.0f - thx * thx) * inv_s;
        const float ddy = tt * (1.0f - thy * thy) * inv_s;
        const float det = ddx * ddy;

        float gx = (thx * inv_s + 1.0f) * 512.0f - 0.5f;
        float gy = (thy * inv_s + 1.0f) * 512.0f - 0.5f;
        gx = fminf(fmaxf(gx, 0.0f), (float)(WI - 1));
        gy = fminf(fmaxf(gy, 0.0f), (float)(HI - 1));

        const int xb = min((int)gx, WI - 2);
        const int yb = min((int)gy, HI - 2);
        const float fx = gx - (float)xb;
        const float fy = gy - (float)yb;

        const float w00 = (1.0f - fx) * (1.0f - fy) * det;
        const float w01 = fx * (1.0f - fy) * det;
        const float w10 = (1.0f - fx) * fy * det;
        const float w11 = fx * fy * det;
        dsum += det;

        const int lidx = (yb - y_lo) * nc + (xb - xlo);
        const int l10  = lidx + nc;
        acc0 += w00 * Q0[lidx] + w01 * Q0[lidx + 1] + w10 * Q0[l10] + w11 * Q0[l10 + 1];
        acc1 += w00 * Q1[lidx] + w01 * Q1[lidx + 1] + w10 * Q1[l10] + w11 * Q1[l10 + 1];
        acc2 += w00 * Q2[lidx] + w01 * Q2[lidx + 1] + w10 * Q2[l10] + w11 * Q2[l10 + 1];
    };

    auto sample_glb = [&](float jx, float jy, float pxb) {
        const float posx = pxb + jx * step;
        const float posy = py + jy * step;

        const float thx = fast_tanh(tt * posx);
        const float thy = fast_tanh(tt * posy);
        const float ddx = tt * (1.0f - thx * thx) * inv_s;
        const float ddy = tt * (1.0f - thy * thy) * inv_s;
        const float det = ddx * ddy;

        float gx = (thx * inv_s + 1.0f) * 512.0f - 0.5f;
        float gy = (thy * inv_s + 1.0f) * 512.0f - 0.5f;
        gx = fminf(fmaxf(gx, 0.0f), (float)(WI - 1));
        gy = fminf(fmaxf(gy, 0.0f), (float)(HI - 1));

        const int xb = min((int)gx, WI - 2);
        const int yb = min((int)gy, HI - 2);
        const float fx = gx - (float)xb;
        const float fy = gy - (float)yb;

        const float w00 = (1.0f - fx) * (1.0f - fy) * det;
        const float w01 = fx * (1.0f - fy) * det;
        const float w10 = (1.0f - fx) * fy * det;
        const float w11 = fx * fy * det;
        dsum += det;

        const int i0 = yb * WI + xb;
        const int i1 = i0 + WI;
        { const float a0 = p0[i0], a1 = p0[i0 + 1], c0 = p0[i1], c1 = p0[i1 + 1];
          acc0 += a0 * w00 + a1 * w01 + c0 * w10 + c1 * w11; }
        { const float a0 = p1[i0], a1 = p1[i0 + 1], c0 = p1[i1], c1 = p1[i1 + 1];
          acc1 += a0 * w00 + a1 * w01 + c0 * w10 + c1 * w11; }
        { const float a0 = p2[i0], a1 = p2[i0 + 1], c0 = p2[i1], c1 = p2[i1 + 1];
          acc2 += a0 * w00 + a1 * w01 + c0 * w10 + c1 * w11; }
    };

    #define JLOAD(P, KOFF)                                                   \
        P##0 = jit2[jb0 + (KOFF)];           P##1 = jit2[jb0 + (KOFF) + 1 * SS]; \
        P##2 = jit2[jb0 + (KOFF) + 2 * SS];  P##3 = jit2[jb0 + (KOFF) + 3 * SS]; \
        P##4 = jit2[jb0 + (KOFF) + 4 * SS];  P##5 = jit2[jb0 + (KOFF) + 5 * SS]; \
        P##6 = jit2[jb0 + (KOFF) + 6 * SS];  P##7 = jit2[jb0 + (KOFF) + 7 * SS];

    // Async DMA stage: fire-and-forget, zero data registers.
    #define STAGE(D0, D1, D2, XL, NC)                                        \
        { const int np_ = nrows * (NC);                                      \
          const int ni_ = (np_ + 63) >> 6;                                   \
          const unsigned md_ = (1u << 22) / (unsigned)(NC) + 1u;             \
          _Pragma("unroll")                                                  \
          for (int kk = 0; kk < NITER; ++kk) {                               \
              if (kk < ni_) {                                                \
                  const int i_ = min(kk * 64 + lane, np_ - 1);               \
                  const int r_ = (int)(((unsigned)i_ * md_) >> 22);          \
                  const int c_ = i_ - r_ * (NC);                             \
                  const int g_ = (y_lo + r_) * WI + ((XL) + c_);             \
                  __builtin_amdgcn_global_load_lds(AS1C(p0 + g_), AS3(D0 + kk * 64), 4, 0, 0); \
                  __builtin_amdgcn_global_load_lds(AS1C(p1 + g_), AS3(D1 + kk * 64), 4, 0, 0); \
                  __builtin_amdgcn_global_load_lds(AS1C(p2 + g_), AS3(D2 + kk * 64), 4, 0, 0); \
              } } }

    #define VMCNT0                                                           \
        asm volatile("s_waitcnt vmcnt(0)" ::: "memory");                     \
        __builtin_amdgcn_sched_barrier(0)

    // "J##0 .x" spacing: "0.x" would lex as one pp-number (R14 lesson).
    #define SAMPLE8(J, PXB_, XL_, NC_, Q0_, Q1_, Q2_)                        \
        acc0 = acc1 = acc2 = dsum = 0.0f;                                    \
        sample(J##0 .x, J##0 .y, PXB_, XL_, NC_, Q0_, Q1_, Q2_);             \
        sample(J##1 .x, J##1 .y, PXB_, XL_, NC_, Q0_, Q1_, Q2_);             \
        sample(J##2 .x, J##2 .y, PXB_, XL_, NC_, Q0_, Q1_, Q2_);             \
        sample(J##3 .x, J##3 .y, PXB_, XL_, NC_, Q0_, Q1_, Q2_);             \
        sample(J##4 .x, J##4 .y, PXB_, XL_, NC_, Q0_, Q1_, Q2_);             \
        sample(J##5 .x, J##5 .y, PXB_, XL_, NC_, Q0_, Q1_, Q2_);             \
        sample(J##6 .x, J##6 .y, PXB_, XL_, NC_, Q0_, Q1_, Q2_);             \
        sample(J##7 .x, J##7 .y, PXB_, XL_, NC_, Q0_, Q1_, Q2_);

    // Combine spp halves across lane pair (+-32), lane<32 stores.
    #define FINISH(K)                                                        \
        acc0 += __shfl_xor(acc0, 32); acc1 += __shfl_xor(acc1, 32);          \
        acc2 += __shfl_xor(acc2, 32); dsum += __shfl_xor(dsum, 32);          \
        if (h == 0) {                                                        \
            const float inv_d = 1.0f / dsum;                                 \
            const int pix = sy * SW + sx00 + (K) * 8 + lx;                   \
            const size_t ob = (size_t)b * CH * SS + pix;                     \
            out[ob]          = acc0 * inv_d;                                 \
            out[ob + SS]     = acc1 * inv_d;                                 \
            out[ob + 2 * SS] = acc2 * inv_d;                                 \
        }

    #define PXB(K) (-1.0f + (sx00 + (K) * 8 + lx) * step)

    // Phase: load next tile's jitter + fire its DMA, then sample current.
    #define PHASE(K, KN, S0, S1, S2, D0, D1, D2, JC, JN)                     \
        JLOAD(JN, (KN) * 8);                                                 \
        STAGE(D0, D1, D2, xl##KN, nc##KN);                                   \
        SAMPLE8(JC, PXB(K), xl##K, nc##K, S0, S1, S2);                       \
        FINISH(K);                                                           \
        VMCNT0;

    if (fits) {
        // prologue: tile0 -> A (the only fully-exposed HBM wait)
        JLOAD(jA, 0);
        STAGE(A0, A1, A2, xl0, nc0);
        VMCNT0;

        PHASE(0, 1, A0, A1, A2, B0, B1, B2, jA, jB);
        PHASE(1, 2, B0, B1, B2, A0, A1, A2, jB, jA);
        PHASE(2, 3, A0, A1, A2, B0, B1, B2, jA, jB);
        PHASE(3, 4, B0, B1, B2, A0, A1, A2, jB, jA);
        PHASE(4, 5, A0, A1, A2, B0, B1, B2, jA, jB);
        PHASE(5, 6, B0, B1, B2, A0, A1, A2, jB, jA);
        PHASE(6, 7, A0, A1, A2, B0, B1, B2, jA, jB);

        // tile7: sample B (nothing left to stage)
        SAMPLE8(jB, PXB(7), xl7, nc7, B0, B1, B2);
        FINISH(7);
    } else {
        // Fallback: direct global gathers (never taken at t=1)
        for (int k = 0; k < 8; ++k) {
            JLOAD(jA, k * 8);
            acc0 = acc1 = acc2 = dsum = 0.0f;
            const float pxb = -1.0f + (sx00 + k * 8 + lx) * step;
            sample_glb(jA0.x, jA0.y, pxb);  sample_glb(jA1.x, jA1.y, pxb);
            sample_glb(jA2.x, jA2.y, pxb);  sample_glb(jA3.x, jA3.y, pxb);
            sample_glb(jA4.x, jA4.y, pxb);  sample_glb(jA5.x, jA5.y, pxb);
            sample_glb(jA6.x, jA6.y, pxb);  sample_glb(jA7.x, jA7.y, pxb);
            acc0 += __shfl_xor(acc0, 32); acc1 += __shfl_xor(acc1, 32);
            acc2 += __shfl_xor(acc2, 32); dsum += __shfl_xor(dsum, 32);
            if (h == 0) {
                const float inv_d = 1.0f / dsum;
                const int pix = sy * SW + sx00 + k * 8 + lx;
                const size_t ob = (size_t)b * CH * SS + pix;
                out[ob]          = acc0 * inv_d;
                out[ob + SS]     = acc1 * inv_d;
                out[ob + 2 * SS] = acc2 * inv_d;
            }
        }
    }

    #undef JLOAD
    #undef STAGE
    #undef VMCNT0
    #undef SAMPLE8
    #undef FINISH
    #undef PXB
    #undef PHASE
}

extern "C" void kernel_launch(void* const* d_in, const int* in_sizes, int n_in,
                              void* d_out, int out_size, void* d_ws, size_t ws_size,
                              hipStream_t stream) {
    const float* img    = (const float*)d_in[0];
    const float* t      = (const float*)d_in[1];
    const float* jitter = (const float*)d_in[2];
    float* out          = (float*)d_out;

    // 8192 tiles of 8x4 px, 8 per wave -> 1024 blocks x 64 threads
    hipLaunchKernelGGL(foveated_chain8, dim3(1024), dim3(NTHR), 0, stream,
                       img, t, jitter, out);
}

// Round 17
// 101.450 us; speedup vs baseline: 8.6610x; 1.0691x over previous
//
#include <hip/hip_runtime.h>
#include <hip/hip_fp16.h>

// Problem constants (from reference)
#define SPP   16
#define SH    256
#define SW    256
#define HI    1024
#define WI    1024
#define CH    3
#define BATCH 4

#define TS    8     // sensor tile = 8x8 px per WAVE, 1 px per lane, 16 spp in-lane
#define MAXD  46    // exact max bbox at t=1: floor-diff(8px*5.2517) + 4 = 46
#define PLN   2176  // LDS plane dwords: ceil(46*46/64)*64
#define NITER 34    // PLN/64 staging issues per channel
#define NTHR  64    // one wave per block

#define AS1C(p) ((const __attribute__((address_space(1))) void*)(p))
#define AS3(p)  ((__attribute__((address_space(3))) void*)(p))

// tanh via v_exp_f32; |arg| <= ~1.2 here, abs error ~1e-6 (threshold 1.7e-2).
__device__ __forceinline__ float fast_tanh(float x) {
    const float e = __expf(2.0f * x);
    return (e - 1.0f) * __builtin_amdgcn_rcpf(e + 1.0f);
}

// FINAL (session best, R8): wave-synchronous 8x8-tile kernel.
//  - 1 px/lane, 16 spp in-lane: coalesced jitter loads (8x64B runs/spp),
//    contiguous stores, zero shuffles.
//  - All 16 jitter loads issued FIRST (named regs, static consumers);
//    their latency hides under the staging DMA.
//  - Staging via async global_load_lds width-4 DMA into packed f32 planes
//    (LDS index = bbox-linear i -> wave-uniform base + lane*4, m104/m108);
//    fixed trip count, fully unrolled, ONE vmcnt(0) drain, no barrier.
// Session finding: ~33us kernel floor is structural (all pipes <25% busy;
// 12 structural variants — occupancy x2, DMA, duty-cycle pipelines, burst
// staging — all land 33-65us). Best measured: this kernel, dur_us 105.5.
__global__ __launch_bounds__(NTHR, 4) void foveated_wave8(
    const float* __restrict__ img,
    const float* __restrict__ t_ptr,
    const float* __restrict__ jitter,
    float* __restrict__ out)
{
    __shared__ float lds_f[CH][PLN];   // 3 x 2176 x 4 B = 26112 B, one wave/block

    // XCD slab swizzle: 4096 blocks -> each XCD gets 512 contiguous logical
    // blocks (contiguous sensor rows -> overlapping bboxes stay in one L2).
    const int bid  = blockIdx.x;
    const int L    = (bid & 7) * 512 + (bid >> 3);
    const int b    = L >> 10;            // 1024 tiles per batch (32x32 of 8x8)
    const int rem  = L & 1023;
    const int trow = rem >> 5;
    const int tcol = rem & 31;
    const int sx0  = tcol * TS;
    const int sy0  = trow * TS;

    const int lane = threadIdx.x;        // 0..63
    const int sx   = sx0 + (lane & 7);
    const int sy   = sy0 + (lane >> 3);

    const float step  = 2.0f / 256.0f;
    const float tt    = t_ptr[0];
    const float inv_s = __builtin_amdgcn_rcpf(fast_tanh(tt));

    // Uniform bbox of this wave's tile (warp is monotone/separable for t>0).
    auto gmap = [&](float p) {
        float g = (fast_tanh(tt * p) * inv_s + 1.0f) * 512.0f - 0.5f;
        return fminf(fmaxf(g, 0.0f), 1023.0f);
    };
    const float pxmin = -1.0f + sx0 * step, pxmax = pxmin + TS * step;
    const float pymin = -1.0f + sy0 * step, pymax = pymin + TS * step;
    const int x_lo = max((int)gmap(pxmin) - 1, 0);
    const int x_hi = min((int)gmap(pxmax) + 2, WI - 1);
    const int y_lo = max((int)gmap(pymin) - 1, 0);
    const int y_hi = min((int)gmap(pymax) + 2, HI - 1);
    const int ncols = x_hi - x_lo + 1;
    const int nrows = y_hi - y_lo + 1;
    const bool fits = (ncols > 0) && (nrows > 0) &&
                      (ncols <= MAXD) && (nrows <= MAXD);  // always true at t=1

    const size_t plane = (size_t)HI * WI;
    const float* __restrict__ p0 = img + (size_t)(b * CH) * plane;
    const float* __restrict__ p1 = p0 + plane;
    const float* __restrict__ p2 = p1 + plane;

    const float px = -1.0f + sx * step;
    const float py = -1.0f + sy * step;

    // ---- Issue ALL 16 jitter loads first (coalesced: 64 consecutive px per
    // plane). Named registers, static consumers -> VGPRs (rule #20). Their
    // latency hides under the staging DMA; the single vmcnt(0) drains both. ----
    const float2* __restrict__ jit2 = (const float2*)jitter;
    const int jbase = sy * SW + sx;
    const float2 jv0  = jit2[jbase +  0 * (SH * SW)];
    const float2 jv1  = jit2[jbase +  1 * (SH * SW)];
    const float2 jv2  = jit2[jbase +  2 * (SH * SW)];
    const float2 jv3  = jit2[jbase +  3 * (SH * SW)];
    const float2 jv4  = jit2[jbase +  4 * (SH * SW)];
    const float2 jv5  = jit2[jbase +  5 * (SH * SW)];
    const float2 jv6  = jit2[jbase +  6 * (SH * SW)];
    const float2 jv7  = jit2[jbase +  7 * (SH * SW)];
    const float2 jv8  = jit2[jbase +  8 * (SH * SW)];
    const float2 jv9  = jit2[jbase +  9 * (SH * SW)];
    const float2 jv10 = jit2[jbase + 10 * (SH * SW)];
    const float2 jv11 = jit2[jbase + 11 * (SH * SW)];
    const float2 jv12 = jit2[jbase + 12 * (SH * SW)];
    const float2 jv13 = jit2[jbase + 13 * (SH * SW)];
    const float2 jv14 = jit2[jbase + 14 * (SH * SW)];
    const float2 jv15 = jit2[jbase + 15 * (SH * SW)];

    float acc0 = 0.0f, acc1 = 0.0f, acc2 = 0.0f, dsum = 0.0f;

    float* __restrict__ P0 = &lds_f[0][0];
    float* __restrict__ P1 = &lds_f[1][0];
    float* __restrict__ P2 = &lds_f[2][0];

    auto sample_lds = [&](float jx, float jy) {
        const float posx = px + jx * step;
        const float posy = py + jy * step;

        const float thx = fast_tanh(tt * posx);
        const float thy = fast_tanh(tt * posy);
        const float ddx = tt * (1.0f - thx * thx) * inv_s;
        const float ddy = tt * (1.0f - thy * thy) * inv_s;
        const float det = ddx * ddy;

        float gx = (thx * inv_s + 1.0f) * 512.0f - 0.5f;
        float gy = (thy * inv_s + 1.0f) * 512.0f - 0.5f;
        gx = fminf(fmaxf(gx, 0.0f), (float)(WI - 1));
        gy = fminf(fmaxf(gy, 0.0f), (float)(HI - 1));

        const int xb = min((int)gx, WI - 2);
        const int yb = min((int)gy, HI - 2);
        const float fx = gx - (float)xb;
        const float fy = gy - (float)yb;

        const float w00 = (1.0f - fx) * (1.0f - fy) * det;
        const float w01 = fx * (1.0f - fy) * det;
        const float w10 = (1.0f - fx) * fy * det;
        const float w11 = fx * fy * det;
        dsum += det;

        // Packed planar layout: LDS index = row*ncols + col.
        const int lidx = (yb - y_lo) * ncols + (xb - x_lo);
        const int l10  = lidx + ncols;

        acc0 += w00 * P0[lidx] + w01 * P0[lidx + 1] + w10 * P0[l10] + w11 * P0[l10 + 1];
        acc1 += w00 * P1[lidx] + w01 * P1[lidx + 1] + w10 * P1[l10] + w11 * P1[l10 + 1];
        acc2 += w00 * P2[lidx] + w01 * P2[lidx + 1] + w10 * P2[l10] + w11 * P2[l10 + 1];
    };

    auto sample_glb = [&](float jx, float jy) {
        const float posx = px + jx * step;
        const float posy = py + jy * step;

        const float thx = fast_tanh(tt * posx);
        const float thy = fast_tanh(tt * posy);
        const float ddx = tt * (1.0f - thx * thx) * inv_s;
        const float ddy = tt * (1.0f - thy * thy) * inv_s;
        const float det = ddx * ddy;

        float gx = (thx * inv_s + 1.0f) * 512.0f - 0.5f;
        float gy = (thy * inv_s + 1.0f) * 512.0f - 0.5f;
        gx = fminf(fmaxf(gx, 0.0f), (float)(WI - 1));
        gy = fminf(fmaxf(gy, 0.0f), (float)(HI - 1));

        const int xb = min((int)gx, WI - 2);
        const int yb = min((int)gy, HI - 2);
        const float fx = gx - (float)xb;
        const float fy = gy - (float)yb;

        const float w00 = (1.0f - fx) * (1.0f - fy) * det;
        const float w01 = fx * (1.0f - fy) * det;
        const float w10 = (1.0f - fx) * fy * det;
        const float w11 = fx * fy * det;
        dsum += det;

        const int i0 = yb * WI + xb;
        const int i1 = i0 + WI;
        { const float a0 = p0[i0], a1 = p0[i0 + 1], c0 = p0[i1], c1 = p0[i1 + 1];
          acc0 += a0 * w00 + a1 * w01 + c0 * w10 + c1 * w11; }
        { const float a0 = p1[i0], a1 = p1[i0 + 1], c0 = p1[i1], c1 = p1[i1 + 1];
          acc1 += a0 * w00 + a1 * w01 + c0 * w10 + c1 * w11; }
        { const float a0 = p2[i0], a1 = p2[i0 + 1], c0 = p2[i1], c1 = p2[i1 + 1];
          acc2 += a0 * w00 + a1 * w01 + c0 * w10 + c1 * w11; }
    };

    if (fits) {
        // ---- Async-stage bbox -> LDS planes via global_load_lds width 4.
        // Fixed trip count, fully unrolled, clamped index: all ~102 requests
        // go into flight back-to-back; one vmcnt(0) drain at the end. LDS
        // dest is wave-uniform base + lane*4 (HW rule); global src per-lane. ----
        const int npix  = nrows * ncols;
        const int niter = (npix + 63) >> 6;                      // <= NITER
        const unsigned mdiv = (1u << 22) / (unsigned)ncols + 1u; // i<4096: exact
        #pragma unroll
        for (int k = 0; k < NITER; ++k) {
            if (k < niter) {   // wave-uniform branch
                int i = k * 64 + lane;
                i = min(i, npix - 1);           // clamp: valid addr, dup write in pad
                const int r = (int)(((unsigned)i * mdiv) >> 22);
                const int c = i - r * ncols;
                const int g = (y_lo + r) * WI + (x_lo + c);
                __builtin_amdgcn_global_load_lds(AS1C(p0 + g), AS3(P0 + k * 64), 4, 0, 0);
                __builtin_amdgcn_global_load_lds(AS1C(p1 + g), AS3(P1 + k * 64), 4, 0, 0);
                __builtin_amdgcn_global_load_lds(AS1C(p2 + g), AS3(P2 + k * 64), 4, 0, 0);
            }
        }
        // Same wave produced and consumes: single vmcnt drain, no barrier.
        asm volatile("s_waitcnt vmcnt(0)" ::: "memory");
        __builtin_amdgcn_sched_barrier(0);

        // ---- This lane's 16 spp from LDS (fully unrolled, independent chains) ----
        sample_lds(jv0.x,  jv0.y);   sample_lds(jv1.x,  jv1.y);
        sample_lds(jv2.x,  jv2.y);   sample_lds(jv3.x,  jv3.y);
        sample_lds(jv4.x,  jv4.y);   sample_lds(jv5.x,  jv5.y);
        sample_lds(jv6.x,  jv6.y);   sample_lds(jv7.x,  jv7.y);
        sample_lds(jv8.x,  jv8.y);   sample_lds(jv9.x,  jv9.y);
        sample_lds(jv10.x, jv10.y);  sample_lds(jv11.x, jv11.y);
        sample_lds(jv12.x, jv12.y);  sample_lds(jv13.x, jv13.y);
        sample_lds(jv14.x, jv14.y);  sample_lds(jv15.x, jv15.y);
    } else {
        // ---- Fallback: direct global gathers (never taken at t=1) ----
        sample_glb(jv0.x,  jv0.y);   sample_glb(jv1.x,  jv1.y);
        sample_glb(jv2.x,  jv2.y);   sample_glb(jv3.x,  jv3.y);
        sample_glb(jv4.x,  jv4.y);   sample_glb(jv5.x,  jv5.y);
        sample_glb(jv6.x,  jv6.y);   sample_glb(jv7.x,  jv7.y);
        sample_glb(jv8.x,  jv8.y);   sample_glb(jv9.x,  jv9.y);
        sample_glb(jv10.x, jv10.y);  sample_glb(jv11.x, jv11.y);
        sample_glb(jv12.x, jv12.y);  sample_glb(jv13.x, jv13.y);
        sample_glb(jv14.x, jv14.y);  sample_glb(jv15.x, jv15.y);
    }

    // ---- 1 px per lane: no reduction, contiguous stores ----
    const float inv_d = 1.0f / dsum;
    const int pix = sy * SW + sx;
    const size_t ob = (size_t)b * CH * (SH * SW) + pix;
    out[ob]                 = acc0 * inv_d;
    out[ob + (SH * SW)]     = acc1 * inv_d;
    out[ob + 2 * (SH * SW)] = acc2 * inv_d;
}

extern "C" void kernel_launch(void* const* d_in, const int* in_sizes, int n_in,
                              void* d_out, int out_size, void* d_ws, size_t ws_size,
                              hipStream_t stream) {
    const float* img    = (const float*)d_in[0];
    const float* t      = (const float*)d_in[1];
    const float* jitter = (const float*)d_in[2];
    float* out          = (float*)d_out;

    // 4 batches x 32x32 tiles of 8x8 px = 4096 blocks, 64 threads (1 wave)
    hipLaunchKernelGGL(foveated_wave8, dim3(4096), dim3(NTHR), 0, stream,
                       img, t, jitter, out);
}